// Round 8
// baseline (88.903 us; speedup 1.0000x reference)
//
#include <hip/hip_runtime.h>
#include <math.h>

typedef float vf4 __attribute__((ext_vector_type(4)));

__device__ __forceinline__ float wave_reduce_sum(float v) {
    #pragma unroll
    for (int off = 32; off > 0; off >>= 1)
        v += __shfl_xor(v, off, 64);
    return v;
}

// fast tanh: tanh(x) = 1 - 2/(exp(2x)+1); exp via v_exp, recip via v_rcp
__device__ __forceinline__ float fast_tanh(float x) {
    float e = __expf(2.0f * x);
    return 1.0f - 2.0f * __builtin_amdgcn_rcpf(e + 1.0f);
}

// Kernel 1: rec[b*H + h] = dot(rnn_state[b,:], W_rec[h,:])
// Block 0 additionally zeroes the per-b softmax accumulator (d_ws is NOT
// re-poisoned between graph replays, so this must happen every call).
__global__ void rec_kernel(const float* __restrict__ rnn,
                           const float* __restrict__ Wrec,
                           float* __restrict__ rec,
                           float* __restrict__ sumb,
                           int B, int H, int R) {
    if (blockIdx.x == 0 && threadIdx.x < 32) sumb[threadIdx.x] = 0.0f;

    int w    = (blockIdx.x * blockDim.x + threadIdx.x) >> 6;
    int lane = threadIdx.x & 63;
    int nOut = B * H;
    if (w >= nOut) return;
    int b = w / H;
    int h = w - b * H;
    const float* xr = rnn  + (size_t)b * R;
    const float* wr = Wrec + (size_t)h * R;
    float acc = 0.f;
    for (int r = lane * 4; r < R; r += 256) {
        vf4 a = *(const vf4*)(xr + r);
        vf4 c = *(const vf4*)(wr + r);
        acc += a.x * c.x + a.y * c.y + a.z * c.z + a.w * c.w;
    }
    acc = wave_reduce_sum(acc);
    if (lane == 0) rec[w] = acc;
}

// Kernel 2: each wave owns a fixed b and SCORE_ROWS consecutive t values.
// Per-row partials in acc[16]; one batched tree-reduce per strip. NO-MAX
// softmax: lanes 0..15 compute p = exp(score + bias + mask) directly,
// store p (unnormalized weight) coalesced into (B,T), reduce the strip's
// 16 p-values and atomicAdd one partial per strip into sumb[b].
#define SCORE_ROWS 16
__global__ void score_kernel(const float* __restrict__ enc,
                             const float* __restrict__ mask,
                             const float* __restrict__ rec,
                             const float* __restrict__ wsc,
                             const float* __restrict__ bsc,
                             float* __restrict__ p_t,    // (B,T) unnormalized
                             float* __restrict__ sumb,   // (B,)
                             int T, int B, int H) {
    const int w    = (blockIdx.x * blockDim.x + threadIdx.x) >> 6;
    const int lane = threadIdx.x & 63;
    const int b     = w % B;
    const int tbase = (w / B) * SCORE_ROWS;
    if (tbase >= T) return;

    const int h0 = lane * 4;          // first half: h in [0, H/2)
    const int h1 = (H >> 1) + h0;     // second half

    const float* rr = rec + (size_t)b * H;
    vf4 r0 = *(const vf4*)(rr + h0);
    vf4 r1 = *(const vf4*)(rr + h1);
    vf4 w0 = *(const vf4*)(wsc + h0);
    vf4 w1 = *(const vf4*)(wsc + h1);
    const float bias = bsc[0];

    const float* erow = enc + ((size_t)tbase * B + b) * H;
    const size_t rstride = (size_t)B * H;

    float acc[SCORE_ROWS];
    #pragma unroll
    for (int i = 0; i < SCORE_ROWS; ++i) {
        const float* er = erow + (size_t)i * rstride;
        vf4 e0 = *(const vf4*)(er + h0);
        vf4 e1 = *(const vf4*)(er + h1);
        float a;
        a  = w0.x * fast_tanh(e0.x + r0.x);
        a += w0.y * fast_tanh(e0.y + r0.y);
        a += w0.z * fast_tanh(e0.z + r0.z);
        a += w0.w * fast_tanh(e0.w + r0.w);
        a += w1.x * fast_tanh(e1.x + r1.x);
        a += w1.y * fast_tanh(e1.y + r1.y);
        a += w1.z * fast_tanh(e1.z + r1.z);
        a += w1.w * fast_tanh(e1.w + r1.w);
        acc[i] = a;
    }

    // fold stages: 16 -> 8 -> 4 -> 2 -> 1 values across lane bits 0..3
    #pragma unroll
    for (int s = 0; s < 4; ++s) {
        const int bit = 1 << s;
        #pragma unroll
        for (int i = 0; i < (SCORE_ROWS >> (s + 1)); ++i) {
            float sent = (lane & bit) ? acc[2 * i]     : acc[2 * i + 1];
            float keep = (lane & bit) ? acc[2 * i + 1] : acc[2 * i];
            acc[i] = keep + __shfl_xor(sent, bit, 64);
        }
    }
    acc[0] += __shfl_xor(acc[0], 16, 64);
    acc[0] += __shfl_xor(acc[0], 32, 64);
    // every lane now holds the full sum for row (lane & 15)

    if (lane < SCORE_ROWS) {
        const int t = tbase + lane;
        float sc = acc[0] + bias + mask[(size_t)t * B + b];
        float p  = __expf(sc);               // |sc| <= ~20 (or -1e5 -> 0): safe
        p_t[(size_t)b * T + t] = p;
        // 16-lane strip sum (xor partners of lanes 0..15 stay in 0..15)
        float s = p;
        s += __shfl_xor(s, 1, 64);
        s += __shfl_xor(s, 2, 64);
        s += __shfl_xor(s, 4, 64);
        s += __shfl_xor(s, 8, 64);
        if (lane == 0) atomicAdd(&sumb[b], s);
    }
}

// Kernel 3: finalize. 64t x 32b tile per block: coalesced load from (B,T),
// LDS transpose (padded, conflict-free), scale by 1/sumb[b], coalesced
// 128B stores to (T,B) out.
__global__ void finalize_kernel(const float* __restrict__ p_t,
                                const float* __restrict__ sumb,
                                float* __restrict__ out, int T, int B) {
    __shared__ float tile[32][65];
    __shared__ float si[32];
    const int tid = threadIdx.x;
    const int t0  = blockIdx.x * 64;

    if (tid < B) si[tid] = 1.0f / sumb[tid];
    __syncthreads();

    #pragma unroll
    for (int i = 0; i < 8; ++i) {
        int idx  = i * 256 + tid;
        int brow = idx >> 6;                 // 0..31
        int tcol = idx & 63;                 // 0..63
        tile[brow][tcol] = p_t[(size_t)brow * T + t0 + tcol];
    }
    __syncthreads();

    #pragma unroll
    for (int i = 0; i < 8; ++i) {
        int idx  = i * 256 + tid;
        int trow = idx >> 5;                 // 0..63
        int bcol = idx & 31;                 // 0..31
        out[(size_t)(t0 + trow) * B + bcol] = tile[bcol][trow] * si[bcol];
    }
}

extern "C" void kernel_launch(void* const* d_in, const int* in_sizes, int n_in,
                              void* d_out, int out_size, void* d_ws, size_t ws_size,
                              hipStream_t stream) {
    const float* enc  = (const float*)d_in[0];  // (T,B,H)
    const float* mask = (const float*)d_in[1];  // (T,B)
    const float* rnn  = (const float*)d_in[2];  // (B,R)
    // d_in[3] = prev_att_weights, unused by the reference
    const float* Wrec = (const float*)d_in[4];  // (H,R)
    const float* wsc  = (const float*)d_in[5];  // (H,)
    const float* bsc  = (const float*)d_in[6];  // (1,)

    const int H = in_sizes[5];
    const int R = in_sizes[4] / H;
    const int B = in_sizes[2] / R;
    const int T = in_sizes[1] / B;

    float* rec  = (float*)d_ws;                 // B*H floats
    float* p_t  = rec + (size_t)B * H;          // (B,T) floats
    float* sumb = p_t + (size_t)B * T;          // B floats
    float* out  = (float*)d_out;                // (T,B)

    // Kernel 1: B*H outputs, one wave each (block 0 zeroes sumb)
    {
        int nOut   = B * H;
        int blocks = (nOut + 3) / 4;
        rec_kernel<<<blocks, 256, 0, stream>>>(rnn, Wrec, rec, sumb, B, H, R);
    }
    // Kernel 2: one wave per (b, 16-row strip)
    {
        int nWaves = (T / SCORE_ROWS) * B;
        int blocks = (nWaves + 3) / 4;
        score_kernel<<<blocks, 256, 0, stream>>>(enc, mask, rec, wsc, bsc,
                                                 p_t, sumb, T, B, H);
    }
    // Kernel 3: one block per 64-t tile
    finalize_kernel<<<T / 64, 256, 0, stream>>>(p_t, sumb, out, T, B);
}

// Round 9
// 56.683 us; speedup vs baseline: 1.5684x; 1.5684x over previous
//
#include <hip/hip_runtime.h>
#include <math.h>

typedef float vf4 __attribute__((ext_vector_type(4)));
typedef float vf2 __attribute__((ext_vector_type(2)));

__device__ __forceinline__ float wave_reduce_sum(float v) {
    #pragma unroll
    for (int off = 32; off > 0; off >>= 1)
        v += __shfl_xor(v, off, 64);
    return v;
}
__device__ __forceinline__ float wave_reduce_max(float v) {
    #pragma unroll
    for (int off = 32; off > 0; off >>= 1)
        v = fmaxf(v, __shfl_xor(v, off, 64));
    return v;
}

// fast tanh: tanh(x) = 1 - 2/(exp(2x)+1); exp via v_exp, recip via v_rcp
__device__ __forceinline__ float fast_tanh(float x) {
    float e = __expf(2.0f * x);
    return 1.0f - 2.0f * __builtin_amdgcn_rcpf(e + 1.0f);
}

// Kernel 1: rec[b*H + h] = dot(rnn_state[b,:], W_rec[h,:])
__global__ void rec_kernel(const float* __restrict__ rnn,
                           const float* __restrict__ Wrec,
                           float* __restrict__ rec,
                           int B, int H, int R) {
    int w    = (blockIdx.x * blockDim.x + threadIdx.x) >> 6;
    int lane = threadIdx.x & 63;
    int nOut = B * H;
    if (w >= nOut) return;
    int b = w / H;
    int h = w - b * H;
    const float* xr = rnn  + (size_t)b * R;
    const float* wr = Wrec + (size_t)h * R;
    float acc = 0.f;
    for (int r = lane * 4; r < R; r += 256) {
        vf4 a = *(const vf4*)(xr + r);
        vf4 c = *(const vf4*)(wr + r);
        acc += a.x * c.x + a.y * c.y + a.z * c.z + a.w * c.w;
    }
    acc = wave_reduce_sum(acc);
    if (lane == 0) rec[w] = acc;
}

// Kernel 2 (R5-proven core): each wave owns fixed b and 16 consecutive t.
// Per-row partials in acc[16]; one batched tree-reduce per strip; coalesced
// 16-lane store into (B,T). enc loads are NONTEMPORAL (single-use stream).
#define SCORE_ROWS 16
__global__ void score_kernel(const float* __restrict__ enc,
                             const float* __restrict__ mask,
                             const float* __restrict__ rec,
                             const float* __restrict__ wsc,
                             const float* __restrict__ bsc,
                             float* __restrict__ scores_t,  // (B,T)
                             int T, int B, int H) {
    const int w    = (blockIdx.x * blockDim.x + threadIdx.x) >> 6;
    const int lane = threadIdx.x & 63;
    const int b     = w % B;
    const int tbase = (w / B) * SCORE_ROWS;
    if (tbase >= T) return;

    const int h0 = lane * 4;          // first half: h in [0, H/2)
    const int h1 = (H >> 1) + h0;     // second half

    const float* rr = rec + (size_t)b * H;
    vf4 r0 = *(const vf4*)(rr + h0);
    vf4 r1 = *(const vf4*)(rr + h1);
    vf4 w0 = *(const vf4*)(wsc + h0);
    vf4 w1 = *(const vf4*)(wsc + h1);
    const float bias = bsc[0];

    const float* erow = enc + ((size_t)tbase * B + b) * H;
    const size_t rstride = (size_t)B * H;

    float acc[SCORE_ROWS];
    #pragma unroll
    for (int i = 0; i < SCORE_ROWS; ++i) {
        const float* er = erow + (size_t)i * rstride;
        vf4 e0 = __builtin_nontemporal_load((const vf4*)(er + h0));
        vf4 e1 = __builtin_nontemporal_load((const vf4*)(er + h1));
        float a;
        a  = w0.x * fast_tanh(e0.x + r0.x);
        a += w0.y * fast_tanh(e0.y + r0.y);
        a += w0.z * fast_tanh(e0.z + r0.z);
        a += w0.w * fast_tanh(e0.w + r0.w);
        a += w1.x * fast_tanh(e1.x + r1.x);
        a += w1.y * fast_tanh(e1.y + r1.y);
        a += w1.z * fast_tanh(e1.z + r1.z);
        a += w1.w * fast_tanh(e1.w + r1.w);
        acc[i] = a;
    }

    // fold stages: 16 -> 8 -> 4 -> 2 -> 1 values across lane bits 0..3
    #pragma unroll
    for (int s = 0; s < 4; ++s) {
        const int bit = 1 << s;
        #pragma unroll
        for (int i = 0; i < (SCORE_ROWS >> (s + 1)); ++i) {
            float sent = (lane & bit) ? acc[2 * i]     : acc[2 * i + 1];
            float keep = (lane & bit) ? acc[2 * i + 1] : acc[2 * i];
            acc[i] = keep + __shfl_xor(sent, bit, 64);
        }
    }
    acc[0] += __shfl_xor(acc[0], 16, 64);
    acc[0] += __shfl_xor(acc[0], 32, 64);

    if (lane < SCORE_ROWS) {
        const int t = tbase + lane;
        scores_t[(size_t)b * T + t] = acc[0] + bias + mask[(size_t)t * B + b];
    }
}

// Kernel 3a: partial softmax stats. Grid = B*CHUNKS blocks; each block (256
// thr) reduces a T/CHUNKS slice of one b-row: local max, local exp-sum.
#define CHUNKS 4
__global__ void stats_partial_kernel(const float* __restrict__ scores_t,
                                     float* __restrict__ pm,   // (CHUNKS,B)
                                     float* __restrict__ ps,   // (CHUNKS,B)
                                     int T, int B) {
    const int blk = blockIdx.x;
    const int b   = blk % B;
    const int c   = blk / B;
    const int L   = T / CHUNKS;              // 1024
    const int tid = threadIdx.x;
    const int wid  = tid >> 6;
    const int lane = tid & 63;
    const float* base = scores_t + (size_t)b * T + (size_t)c * L;

    vf4 v = *(const vf4*)(base + tid * 4);   // 256 thr * 4 = 1024 floats

    __shared__ float redm[4];
    float m = fmaxf(fmaxf(v.x, v.y), fmaxf(v.z, v.w));
    m = wave_reduce_max(m);
    if (lane == 0) redm[wid] = m;
    __syncthreads();
    m = fmaxf(fmaxf(redm[0], redm[1]), fmaxf(redm[2], redm[3]));

    float s = __expf(v.x - m) + __expf(v.y - m)
            + __expf(v.z - m) + __expf(v.w - m);
    s = wave_reduce_sum(s);
    __shared__ float reds[4];
    if (lane == 0) reds[wid] = s;
    __syncthreads();
    if (tid == 0) {
        float ss = (reds[0] + reds[1]) + (reds[2] + reds[3]);
        pm[c * B + b] = m;
        ps[c * B + b] = ss;
    }
}

// Kernel 3b: finalize. Merge CHUNKS partials per b (cheap, redundant per
// block), then 64t x 32b tile: coalesced load from (B,T), LDS transpose,
// exp(x-m)*inv, coalesced 128B stores to (T,B).
__global__ void finalize_kernel(const float* __restrict__ scores_t,
                                const float* __restrict__ pm,
                                const float* __restrict__ ps,
                                float* __restrict__ out, int T, int B) {
    __shared__ float tile[32][65];
    __shared__ float sm[32];
    __shared__ float si[32];
    const int tid = threadIdx.x;
    const int t0  = blockIdx.x * 64;

    if (tid < B) {
        float m = -INFINITY;
        #pragma unroll
        for (int c = 0; c < CHUNKS; ++c)
            m = fmaxf(m, pm[c * B + tid]);
        float s = 0.f;
        #pragma unroll
        for (int c = 0; c < CHUNKS; ++c)
            s += ps[c * B + tid] * __expf(pm[c * B + tid] - m);
        sm[tid] = m;
        si[tid] = 1.0f / s;
    }
    __syncthreads();

    #pragma unroll
    for (int i = 0; i < 8; ++i) {
        int idx  = i * 256 + tid;
        int brow = idx >> 6;                 // 0..31
        int tcol = idx & 63;                 // 0..63
        tile[brow][tcol] = scores_t[(size_t)brow * T + t0 + tcol];
    }
    __syncthreads();

    #pragma unroll
    for (int i = 0; i < 8; ++i) {
        int idx  = i * 256 + tid;
        int trow = idx >> 5;                 // 0..63
        int bcol = idx & 31;                 // 0..31
        float x = tile[bcol][trow];
        float r = __expf(x - sm[bcol]) * si[bcol];
        out[(size_t)(t0 + trow) * B + bcol] = r;
    }
}

extern "C" void kernel_launch(void* const* d_in, const int* in_sizes, int n_in,
                              void* d_out, int out_size, void* d_ws, size_t ws_size,
                              hipStream_t stream) {
    const float* enc  = (const float*)d_in[0];  // (T,B,H)
    const float* mask = (const float*)d_in[1];  // (T,B)
    const float* rnn  = (const float*)d_in[2];  // (B,R)
    // d_in[3] = prev_att_weights, unused by the reference
    const float* Wrec = (const float*)d_in[4];  // (H,R)
    const float* wsc  = (const float*)d_in[5];  // (H,)
    const float* bsc  = (const float*)d_in[6];  // (1,)

    const int H = in_sizes[5];
    const int R = in_sizes[4] / H;
    const int B = in_sizes[2] / R;
    const int T = in_sizes[1] / B;

    float* rec      = (float*)d_ws;                       // B*H floats
    float* scores_t = rec + (size_t)B * H;                // (B,T) floats
    float* pm       = scores_t + (size_t)B * T;           // CHUNKS*B floats
    float* ps       = pm + (size_t)CHUNKS * B;            // CHUNKS*B floats
    float* out      = (float*)d_out;                      // (T,B)

    // Kernel 1: B*H outputs, one wave each
    {
        int nOut   = B * H;
        int blocks = (nOut + 3) / 4;
        rec_kernel<<<blocks, 256, 0, stream>>>(rnn, Wrec, rec, B, H, R);
    }
    // Kernel 2: one wave per (b, 16-row strip)
    {
        int nWaves = (T / SCORE_ROWS) * B;
        int blocks = (nWaves + 3) / 4;
        score_kernel<<<blocks, 256, 0, stream>>>(enc, mask, rec, wsc, bsc,
                                                 scores_t, T, B, H);
    }
    // Kernel 3a: B*CHUNKS blocks
    stats_partial_kernel<<<B * CHUNKS, 256, 0, stream>>>(scores_t, pm, ps, T, B);
    // Kernel 3b: one block per 64-t tile
    finalize_kernel<<<T / 64, 256, 0, stream>>>(scores_t, pm, ps, out, T, B);
}